// Round 2
// baseline (895.358 us; speedup 1.0000x reference)
//
#include <hip/hip_runtime.h>
#include <hip/hip_cooperative_groups.h>
#include <math.h>

namespace cg = cooperative_groups;

#define NN 8
#define RR 256
#define CD 64      // in/out channel dim
#define MM 32      // kept modes per dim
#define KHN 64     // 2*MM kh values (rows 0..31 and 224..255)
#define KWN 32

#define ANG 0.024543692606170259f  // 2*pi/256
#define INVN (1.0f / 65536.0f)     // ortho norm, folded into k3 weights

typedef __attribute__((ext_vector_type(4))) float f32x4;
typedef __attribute__((ext_vector_type(8))) short short8;
typedef unsigned short u16;

__device__ inline u16 f2bf(float f) {
    union { float f; unsigned u; } v; v.f = f;
    unsigned r = v.u + 0x7FFF + ((v.u >> 16) & 1);
    return (u16)(r >> 16);
}
__device__ inline unsigned pack2(float a, float b) {
    return (unsigned)f2bf(a) | ((unsigned)f2bf(b) << 16);
}
__device__ inline int swkey(int row) { return (row & 7) ^ ((row >> 3) & 7); }

// ===================== persistent cooperative mega-kernel ====================
// Phases: P0 tables | P1 DFT-w | P2 DFT-h | P3 spectral | P4 iDFT-h | P5 final
// Shared union: max 36864 B (P3). 4 blocks/CU guaranteed by launch_bounds(256,4).
__global__ __launch_bounds__(256, 4) void mega(
    const float* __restrict__ x, const float* __restrict__ w0,
    const float* __restrict__ w1, const float* __restrict__ res_w,
    const float* __restrict__ res_b,
    u16* __restrict__ X1R, u16* __restrict__ X1I,
    float2* __restrict__ X2, unsigned* __restrict__ X3b,
    u16* __restrict__ Y1R, u16* __restrict__ Y1I,
    u16* __restrict__ A2g, u16* __restrict__ A4g,
    u16* __restrict__ T1g, u16* __restrict__ T5g,
    u16* __restrict__ RWTg, float* __restrict__ out)
{
    cg::grid_group grid = cg::this_grid();
    __shared__ __align__(16) unsigned char SMEM[37120];
    int t = threadIdx.x;
    int b = blockIdx.x;
    int G = gridDim.x;
    int wv = t >> 6, l = t & 63, lm = l & 15, lq = l >> 4;

    // ---------------- P0: twiddle/operand tables ----------------
    {
        int gid = b * 256 + t;
        if (gid < 65536) {
            {
                int r = gid >> 9, k = gid & 511;
                int khIdx = r & 63, part = r >> 6;
                int kh = (khIdx < 32) ? khIdx : 192 + khIdx;
                int h = k & 255, kpart = k >> 8;
                float s, c;
                __sincosf((float)((kh * h) & 255) * ANG, &s, &c);
                float v = (part == 0) ? ((kpart == 0) ? c : s)
                                      : ((kpart == 0) ? -s : c);
                A2g[gid] = f2bf(v);
            }
            {
                int r = gid >> 7, k = gid & 127;
                int h = r & 255, part = r >> 8;
                int khIdx = k & 63, kpart = k >> 6;
                int kh = (khIdx < 32) ? khIdx : 192 + khIdx;
                float s, c;
                __sincosf((float)((kh * h) & 255) * ANG, &s, &c);
                float v = (part == 0) ? ((kpart == 0) ? c : -s)
                                      : ((kpart == 0) ? s : c);
                A4g[gid] = f2bf(v);
            }
            if (gid < 16384) {
                {
                    int r = gid >> 8, w = gid & 255;
                    float s, c;
                    if (r < 32) { __sincosf((float)((r * w) & 255) * ANG, &s, &c); T1g[gid] = f2bf(c); }
                    else        { __sincosf((float)(((r - 32) * w) & 255) * ANG, &s, &c); T1g[gid] = f2bf(-s); }
                }
                {
                    int w = gid >> 6, c = gid & 63;
                    float v;
                    if (c == 0) v = 1.0f;
                    else if (c < 32) { float s, co; __sincosf((float)((c * w) & 255) * ANG, &s, &co); v = 2.0f * co; }
                    else if (c == 32) v = 0.0f;
                    else { float s, co; __sincosf((float)(((c - 32) * w) & 255) * ANG, &s, &co); v = -2.0f * s; }
                    T5g[gid] = f2bf(v);
                }
            }
            if (gid < 4096) {
                int o = gid >> 6, i = gid & 63;
                RWTg[gid] = f2bf(res_w[i * 64 + o]);
            }
        }
    }
    __threadfence();
    grid.sync();

    // ---------------- P1: real DFT along w (2048 tiles) ----------------
    {
        u16* Bt = (u16*)SMEM;
        unsigned* B32 = (unsigned*)SMEM;
        for (int nh = b; nh < NN * RR; nh += G) {
            const float* xr = x + (size_t)nh * (RR * CD);
#pragma unroll
            for (int it = 0; it < 8; ++it) {
                int idx = t + it * 256;
                int q = idx >> 4;
                int c0 = (idx & 15) * 4;
                float4 f0 = *(const float4*)&xr[(2 * q) * 64 + c0];
                float4 f1 = *(const float4*)&xr[(2 * q + 1) * 64 + c0];
                B32[(c0 + 0) * 128 + (q ^ (swkey(c0 + 0) << 2))] = pack2(f0.x, f1.x);
                B32[(c0 + 1) * 128 + (q ^ (swkey(c0 + 1) << 2))] = pack2(f0.y, f1.y);
                B32[(c0 + 2) * 128 + (q ^ (swkey(c0 + 2) << 2))] = pack2(f0.z, f1.z);
                B32[(c0 + 3) * 128 + (q ^ (swkey(c0 + 3) << 2))] = pack2(f0.w, f1.w);
            }
            __syncthreads();
            f32x4 acc[4];
#pragma unroll
            for (int nt = 0; nt < 4; ++nt) { f32x4 z = {0.f, 0.f, 0.f, 0.f}; acc[nt] = z; }
#pragma unroll
            for (int ks = 0; ks < 8; ++ks) {
                short8 a = *(const short8*)&T1g[(wv * 16 + lm) * 256 + ks * 32 + lq * 8];
#pragma unroll
                for (int nt = 0; nt < 4; ++nt) {
                    int c = nt * 16 + lm;
                    short8 bf = *(const short8*)&Bt[c * 256 + ((ks * 32 + lq * 8) ^ (swkey(c) << 3))];
                    acc[nt] = __builtin_amdgcn_mfma_f32_16x16x32_bf16(a, bf, acc[nt], 0, 0, 0);
                }
            }
            int n = nh >> 8, h = nh & 255;
#pragma unroll
            for (int nt = 0; nt < 4; ++nt)
#pragma unroll
                for (int r = 0; r < 4; ++r) {
                    int kwp = wv * 16 + lq * 4 + r;
                    int cc = nt * 16 + lm;
                    u16 v = f2bf(acc[nt][r]);
                    if (kwp < 32) X1R[(((size_t)n * 32 + kwp) * 256 + h) * 64 + cc] = v;
                    else          X1I[(((size_t)n * 32 + (kwp - 32)) * 256 + h) * 64 + cc] = v;
                }
            __syncthreads();
        }
    }
    __threadfence();
    grid.sync();

    // ---------------- P2: complex DFT along h (256 tiles) ----------------
    {
        u16* Bs0 = (u16*)SMEM;
        u16* Bs1 = (u16*)(SMEM + 16384);
        for (int tile = b; tile < NN * KWN; tile += G) {
            int n = tile >> 5, kw = tile & 31;
            const u16* baseR = X1R + ((size_t)n * 32 + kw) * (256 * 64);
            const u16* baseI = X1I + ((size_t)n * 32 + kw) * (256 * 64);
            f32x4 acc[2][4];
#pragma unroll
            for (int mt = 0; mt < 2; ++mt)
#pragma unroll
                for (int nt = 0; nt < 4; ++nt) { f32x4 z = {0.f, 0.f, 0.f, 0.f}; acc[mt][nt] = z; }
            auto stage = [&](int ck, u16* Bp) {
                const u16* src = ((ck < 2) ? baseR : baseI) + (size_t)(ck & 1) * (128 * 64);
                unsigned* B32 = (unsigned*)Bp;
#pragma unroll
                for (int it = 0; it < 2; ++it) {
                    int idx = t + it * 256;        // 0..511
                    int hh2 = idx >> 3;            // 0..63 (h-pair)
                    int g = idx & 7;
                    short8 v0 = *(const short8*)&src[(2 * hh2) * 64 + g * 8];
                    short8 v1 = *(const short8*)&src[(2 * hh2 + 1) * 64 + g * 8];
#pragma unroll
                    for (int j = 0; j < 8; ++j) {
                        int c = g * 8 + j;
                        B32[c * 64 + (hh2 ^ (swkey(c) << 2))] =
                            (unsigned)(u16)v0[j] | ((unsigned)(u16)v1[j] << 16);
                    }
                }
            };
            stage(0, Bs0);
            __syncthreads();
            for (int ck = 0; ck < 4; ++ck) {
                if (ck < 3) stage(ck + 1, ((ck + 1) & 1) ? Bs1 : Bs0);
                const u16* B = (ck & 1) ? Bs1 : Bs0;
#pragma unroll
                for (int ks = 0; ks < 4; ++ks) {
                    short8 a0 = *(const short8*)&A2g[(wv * 32 + lm) * 512 + ck * 128 + ks * 32 + lq * 8];
                    short8 a1 = *(const short8*)&A2g[(wv * 32 + 16 + lm) * 512 + ck * 128 + ks * 32 + lq * 8];
#pragma unroll
                    for (int nt = 0; nt < 4; ++nt) {
                        int c = nt * 16 + lm;
                        short8 bf = *(const short8*)&B[c * 128 + ((ks * 32 + lq * 8) ^ (swkey(c) << 3))];
                        acc[0][nt] = __builtin_amdgcn_mfma_f32_16x16x32_bf16(a0, bf, acc[0][nt], 0, 0, 0);
                        acc[1][nt] = __builtin_amdgcn_mfma_f32_16x16x32_bf16(a1, bf, acc[1][nt], 0, 0, 0);
                    }
                }
                __syncthreads();
            }
#pragma unroll
            for (int mt = 0; mt < 2; ++mt)
#pragma unroll
                for (int nt = 0; nt < 4; ++nt)
#pragma unroll
                    for (int r = 0; r < 4; ++r) {
                        int m = wv * 32 + mt * 16 + lq * 4 + r;   // 0..127
                        int c = nt * 16 + lm;
                        float* dst = (float*)&X2[(((size_t)n * 64 + (m & 63)) * 32 + kw) * 64 + c];
                        dst[m >> 6] = acc[mt][nt][r];
                    }
            __syncthreads();
        }
    }
    __threadfence();
    grid.sync();

    // ---------------- P3: spectral 64x64 complex matmul (2048 tiles) --------
    {
        float2* WsP = (float2*)SMEM;             // 32 KB
        float2* XsP = (float2*)(SMEM + 32768);   // 4 KB
        for (int tile = b; tile < KHN * KWN; tile += G) {
            int khIdx = tile >> 5;
            int kw = tile & 31;
            const float* wsrc = (khIdx < 32)
                ? (w0 + (size_t)(khIdx * 32 + kw) * (64 * 64 * 2))
                : (w1 + (size_t)((khIdx - 32) * 32 + kw) * (64 * 64 * 2));
            const float4* wsrc4 = (const float4*)wsrc;
#pragma unroll
            for (int k = 0; k < 8; ++k) {
                int idx = t + k * 256;
                float4 v = wsrc4[idx];
                WsP[2 * idx]     = make_float2(v.x * INVN, v.y * INVN);
                WsP[2 * idx + 1] = make_float2(v.z * INVN, v.w * INVN);
            }
#pragma unroll
            for (int k = 0; k < 2; ++k) {
                int id2 = t + k * 256;
                int n = id2 >> 6, c = id2 & 63;
                XsP[id2] = X2[(((size_t)n * KHN + khIdx) * KWN + kw) * CD + c];
            }
            __syncthreads();
            int o = t & 63;
            int ng = t >> 6;
#pragma unroll
            for (int p = 0; p < 2; ++p) {
                int n = ng + p * 4;
                float aR = 0.f, aI = 0.f;
#pragma unroll 8
                for (int i = 0; i < 64; ++i) {
                    float2 xv = XsP[n * 64 + i];
                    float2 wv_ = WsP[i * 64 + o];
                    aR += xv.x * wv_.x - xv.y * wv_.y;
                    aI += xv.x * wv_.y + xv.y * wv_.x;
                }
                X3b[(((size_t)n * 32 + kw) * 64 + khIdx) * 64 + o] = pack2(aR, aI);
            }
            __syncthreads();
        }
    }
    __threadfence();
    grid.sync();

    // ---------------- P4: inverse DFT along h (1024 tiles) ----------------
    {
        u16* Bs = (u16*)SMEM;
        unsigned* B32 = (unsigned*)SMEM;
        for (int tile = b; tile < NN * KWN * 4; tile += G) {
            int n = tile >> 7, kw = (tile >> 2) & 31, mh = (tile >> 1) & 1, ac = tile & 1;
            const unsigned* src = X3b + ((size_t)n * 32 + kw) * (64 * 64);
#pragma unroll
            for (int it = 0; it < 8; ++it) {
                int idx = t + it * 256;            // 0..2047
                int khl2 = idx >> 6;               // 0..31
                int o = idx & 63;
                unsigned vA = src[(2 * khl2) * 64 + o];
                unsigned vB = src[(2 * khl2 + 1) * 64 + o];
                int K = swkey(o) << 2;
                B32[o * 64 + (khl2 ^ K)]        = (vA & 0xFFFF) | (vB << 16);
                B32[o * 64 + ((32 + khl2) ^ K)] = (vA >> 16) | (vB & 0xFFFF0000u);
            }
            __syncthreads();
            u16* plane = mh ? Y1I : Y1R;
            f32x4 acc[2][4];
#pragma unroll
            for (int mt = 0; mt < 2; ++mt)
#pragma unroll
                for (int nt = 0; nt < 4; ++nt) { f32x4 z = {0.f, 0.f, 0.f, 0.f}; acc[mt][nt] = z; }
#pragma unroll
            for (int ks = 0; ks < 4; ++ks) {
                short8 a0 = *(const short8*)&A4g[(size_t)(mh * 256 + ac * 128 + wv * 32 + lm) * 128 + ks * 32 + lq * 8];
                short8 a1 = *(const short8*)&A4g[(size_t)(mh * 256 + ac * 128 + wv * 32 + 16 + lm) * 128 + ks * 32 + lq * 8];
#pragma unroll
                for (int nt = 0; nt < 4; ++nt) {
                    int c = nt * 16 + lm;
                    short8 bfr = *(const short8*)&Bs[c * 128 + ((ks * 32 + lq * 8) ^ (swkey(c) << 3))];
                    acc[0][nt] = __builtin_amdgcn_mfma_f32_16x16x32_bf16(a0, bfr, acc[0][nt], 0, 0, 0);
                    acc[1][nt] = __builtin_amdgcn_mfma_f32_16x16x32_bf16(a1, bfr, acc[1][nt], 0, 0, 0);
                }
            }
#pragma unroll
            for (int mt = 0; mt < 2; ++mt)
#pragma unroll
                for (int nt = 0; nt < 4; ++nt)
#pragma unroll
                    for (int r = 0; r < 4; ++r) {
                        int h = ac * 128 + wv * 32 + mt * 16 + lq * 4 + r;
                        int o = nt * 16 + lm;
                        plane[(((size_t)n * 256 + h) * 32 + kw) * 64 + o] = f2bf(acc[mt][nt][r]);
                    }
            __syncthreads();
        }
    }
    __threadfence();
    grid.sync();

    // ------- P5: c2r synthesis + residual + bias + SiLU (4096 tiles) -------
    {
        u16* Xs = (u16*)SMEM;                    // 16 KB
        u16* Bs = (u16*)(SMEM + 16384);          // 16 KB
        float* bsm = (float*)(SMEM + 32768);     // 256 B
        unsigned* X32 = (unsigned*)Xs;
        unsigned* B32 = (unsigned*)Bs;
        if (t < 64) bsm[t] = res_b[t];
        for (int bb = b; bb < NN * RR * 2; bb += G) {
            int nh = bb >> 1, half = bb & 1;
            const float* xb = x + ((size_t)nh * 256 + half * 128) * 64;
#pragma unroll
            for (int it = 0; it < 8; ++it) {
                int idx = t + it * 256;
                int wl = idx >> 4, c4 = idx & 15;
                float4 f = *(const float4*)&xb[wl * 64 + c4 * 4];
                uint2 pv; pv.x = pack2(f.x, f.y); pv.y = pack2(f.z, f.w);
                *(uint2*)&X32[wl * 32 + ((2 * c4) ^ (swkey(wl) << 2))] = pv;
            }
            const u16* YR = Y1R + (size_t)nh * 2048;
            const u16* YI = Y1I + (size_t)nh * 2048;
#pragma unroll
            for (int it = 0; it < 4; ++it) {
                int part = it >> 1;
                int kw2 = t >> 4;                  // 0..15
                int opb = (t & 15) + (it & 1) * 16; // 0..31
                const u16* P = part ? YI : YR;
                unsigned vA = *(const unsigned*)&P[(2 * kw2) * 64 + 2 * opb];
                unsigned vB = *(const unsigned*)&P[(2 * kw2 + 1) * 64 + 2 * opb];
                int o0 = 2 * opb;
                int k2 = part * 16 + kw2;          // u32 col
                B32[o0 * 64 + (k2 ^ (swkey(o0) << 2))]       = (vA & 0xFFFF) | (vB << 16);
                B32[(o0 + 1) * 64 + (k2 ^ (swkey(o0 + 1) << 2))] = (vA >> 16) | (vB & 0xFFFF0000u);
            }
#pragma unroll
            for (int it = 0; it < 2; ++it) {
                int idx = t + it * 256;            // 0..511
                int o = idx >> 3, g = idx & 7;
                uint4 v = *(const uint4*)&RWTg[o * 64 + g * 8];
                *(uint4*)&B32[o * 64 + (8 + (g ^ swkey(o))) * 4] = v;
            }
            __syncthreads();
            f32x4 acc[2][4];
#pragma unroll
            for (int mt = 0; mt < 2; ++mt)
#pragma unroll
                for (int nt = 0; nt < 4; ++nt) { f32x4 z = {0.f, 0.f, 0.f, 0.f}; acc[mt][nt] = z; }
#pragma unroll
            for (int ks = 0; ks < 4; ++ks) {
                int r0 = wv * 32 + lm, r1 = r0 + 16;
                short8 a0, a1;
                if (ks < 2) {
                    a0 = *(const short8*)&T5g[(half * 128 + r0) * 64 + ks * 32 + lq * 8];
                    a1 = *(const short8*)&T5g[(half * 128 + r1) * 64 + ks * 32 + lq * 8];
                } else {
                    a0 = *(const short8*)&Xs[r0 * 64 + (((ks - 2) * 32 + lq * 8) ^ (swkey(r0) << 3))];
                    a1 = *(const short8*)&Xs[r1 * 64 + (((ks - 2) * 32 + lq * 8) ^ (swkey(r1) << 3))];
                }
#pragma unroll
                for (int nt = 0; nt < 4; ++nt) {
                    int c = nt * 16 + lm;
                    short8 bf = *(const short8*)&Bs[c * 128 + ((ks * 32 + lq * 8) ^ (swkey(c) << 3))];
                    acc[0][nt] = __builtin_amdgcn_mfma_f32_16x16x32_bf16(a0, bf, acc[0][nt], 0, 0, 0);
                    acc[1][nt] = __builtin_amdgcn_mfma_f32_16x16x32_bf16(a1, bf, acc[1][nt], 0, 0, 0);
                }
            }
            float* orow = out + ((size_t)nh * 256 + half * 128) * 64;
#pragma unroll
            for (int mt = 0; mt < 2; ++mt)
#pragma unroll
                for (int nt = 0; nt < 4; ++nt)
#pragma unroll
                    for (int r = 0; r < 4; ++r) {
                        int wloc = wv * 32 + mt * 16 + lq * 4 + r;
                        int o = nt * 16 + lm;
                        float v = acc[mt][nt][r] + bsm[o];
                        float sv = v / (1.0f + __expf(-v));
                        orow[wloc * 64 + o] = sv;
                    }
            __syncthreads();
        }
    }
}

// ===================== fallback: 6-kernel pipeline (round-1, verified) ======
__global__ __launch_bounds__(256) void k0_tables(u16* __restrict__ A2g,
                                                 u16* __restrict__ A4g,
                                                 u16* __restrict__ T1g,
                                                 u16* __restrict__ T5g,
                                                 const float* __restrict__ res_w,
                                                 u16* __restrict__ RWTg) {
    int gid = blockIdx.x * 256 + threadIdx.x;
    {
        int r = gid >> 9, k = gid & 511;
        int khIdx = r & 63, part = r >> 6;
        int kh = (khIdx < 32) ? khIdx : 192 + khIdx;
        int h = k & 255, kpart = k >> 8;
        float s, c;
        __sincosf((float)((kh * h) & 255) * ANG, &s, &c);
        float v = (part == 0) ? ((kpart == 0) ? c : s) : ((kpart == 0) ? -s : c);
        A2g[gid] = f2bf(v);
    }
    {
        int r = gid >> 7, k = gid & 127;
        int h = r & 255, part = r >> 8;
        int khIdx = k & 63, kpart = k >> 6;
        int kh = (khIdx < 32) ? khIdx : 192 + khIdx;
        float s, c;
        __sincosf((float)((kh * h) & 255) * ANG, &s, &c);
        float v = (part == 0) ? ((kpart == 0) ? c : -s) : ((kpart == 0) ? s : c);
        A4g[gid] = f2bf(v);
    }
    if (gid < 16384) {
        {
            int r = gid >> 8, w = gid & 255;
            float s, c;
            if (r < 32) { __sincosf((float)((r * w) & 255) * ANG, &s, &c); T1g[gid] = f2bf(c); }
            else        { __sincosf((float)(((r - 32) * w) & 255) * ANG, &s, &c); T1g[gid] = f2bf(-s); }
        }
        {
            int w = gid >> 6, c = gid & 63;
            float v;
            if (c == 0) v = 1.0f;
            else if (c < 32) { float s, co; __sincosf((float)((c * w) & 255) * ANG, &s, &co); v = 2.0f * co; }
            else if (c == 32) v = 0.0f;
            else { float s, co; __sincosf((float)(((c - 32) * w) & 255) * ANG, &s, &co); v = -2.0f * s; }
            T5g[gid] = f2bf(v);
        }
    }
    if (gid < 4096) {
        int o = gid >> 6, i = gid & 63;
        RWTg[gid] = f2bf(res_w[i * 64 + o]);
    }
}

__global__ __launch_bounds__(256) void k1_dft_w(const float* __restrict__ x,
                                                const u16* __restrict__ T1g,
                                                u16* __restrict__ X1R,
                                                u16* __restrict__ X1I) {
    __shared__ __align__(16) u16 Bt[64 * 256];
    unsigned* B32 = (unsigned*)Bt;
    int t = threadIdx.x;
    int nh = blockIdx.x;
    const float* xr = x + (size_t)nh * (RR * CD);
#pragma unroll
    for (int it = 0; it < 8; ++it) {
        int idx = t + it * 256;
        int q = idx >> 4;
        int c0 = (idx & 15) * 4;
        float4 f0 = *(const float4*)&xr[(2 * q) * 64 + c0];
        float4 f1 = *(const float4*)&xr[(2 * q + 1) * 64 + c0];
        B32[(c0 + 0) * 128 + (q ^ (swkey(c0 + 0) << 2))] = pack2(f0.x, f1.x);
        B32[(c0 + 1) * 128 + (q ^ (swkey(c0 + 1) << 2))] = pack2(f0.y, f1.y);
        B32[(c0 + 2) * 128 + (q ^ (swkey(c0 + 2) << 2))] = pack2(f0.z, f1.z);
        B32[(c0 + 3) * 128 + (q ^ (swkey(c0 + 3) << 2))] = pack2(f0.w, f1.w);
    }
    __syncthreads();
    int wv = t >> 6, l = t & 63, lm = l & 15, lq = l >> 4;
    f32x4 acc[4];
#pragma unroll
    for (int nt = 0; nt < 4; ++nt) { f32x4 z = {0.f, 0.f, 0.f, 0.f}; acc[nt] = z; }
#pragma unroll
    for (int ks = 0; ks < 8; ++ks) {
        short8 a = *(const short8*)&T1g[(wv * 16 + lm) * 256 + ks * 32 + lq * 8];
#pragma unroll
        for (int nt = 0; nt < 4; ++nt) {
            int c = nt * 16 + lm;
            short8 bf = *(const short8*)&Bt[c * 256 + ((ks * 32 + lq * 8) ^ (swkey(c) << 3))];
            acc[nt] = __builtin_amdgcn_mfma_f32_16x16x32_bf16(a, bf, acc[nt], 0, 0, 0);
        }
    }
    int n = nh >> 8, h = nh & 255;
#pragma unroll
    for (int nt = 0; nt < 4; ++nt)
#pragma unroll
        for (int r = 0; r < 4; ++r) {
            int kwp = wv * 16 + lq * 4 + r;
            int cc = nt * 16 + lm;
            u16 v = f2bf(acc[nt][r]);
            if (kwp < 32) X1R[(((size_t)n * 32 + kwp) * 256 + h) * 64 + cc] = v;
            else          X1I[(((size_t)n * 32 + (kwp - 32)) * 256 + h) * 64 + cc] = v;
        }
}

__global__ __launch_bounds__(512) void k2_dft_h(const u16* __restrict__ X1R,
                                                const u16* __restrict__ X1I,
                                                const u16* __restrict__ A2g,
                                                float2* __restrict__ X2) {
    __shared__ __align__(16) u16 Bs[2][64 * 128];
    int t = threadIdx.x;
    int n = blockIdx.x >> 5, kw = blockIdx.x & 31;
    const u16* baseR = X1R + ((size_t)n * 32 + kw) * (256 * 64);
    const u16* baseI = X1I + ((size_t)n * 32 + kw) * (256 * 64);
    int wv = t >> 6, l = t & 63, lm = l & 15, lq = l >> 4;
    f32x4 acc[4];
#pragma unroll
    for (int nt = 0; nt < 4; ++nt) { f32x4 z = {0.f, 0.f, 0.f, 0.f}; acc[nt] = z; }
    auto stage = [&](int ck, int buf) {
        const u16* src = ((ck < 2) ? baseR : baseI) + (size_t)(ck & 1) * (128 * 64);
        u16* B = Bs[buf];
#pragma unroll
        for (int it = 0; it < 2; ++it) {
            int idx = t + it * 512;
            int hh = idx >> 3, g = idx & 7;
            short8 v = *(const short8*)&src[hh * 64 + g * 8];
#pragma unroll
            for (int j = 0; j < 8; ++j) {
                int c = g * 8 + j;
                B[c * 128 + (hh ^ (swkey(c) << 3))] = (u16)v[j];
            }
        }
    };
    stage(0, 0);
    __syncthreads();
    for (int ck = 0; ck < 4; ++ck) {
        if (ck < 3) stage(ck + 1, (ck + 1) & 1);
        const u16* B = Bs[ck & 1];
#pragma unroll
        for (int ks = 0; ks < 4; ++ks) {
            short8 a = *(const short8*)&A2g[(wv * 16 + lm) * 512 + ck * 128 + ks * 32 + lq * 8];
#pragma unroll
            for (int nt = 0; nt < 4; ++nt) {
                int c = nt * 16 + lm;
                short8 bf = *(const short8*)&B[c * 128 + ((ks * 32 + lq * 8) ^ (swkey(c) << 3))];
                acc[nt] = __builtin_amdgcn_mfma_f32_16x16x32_bf16(a, bf, acc[nt], 0, 0, 0);
            }
        }
        __syncthreads();
    }
#pragma unroll
    for (int nt = 0; nt < 4; ++nt)
#pragma unroll
        for (int r = 0; r < 4; ++r) {
            int m = wv * 16 + lq * 4 + r;
            int c = nt * 16 + lm;
            float* dst = (float*)&X2[(((size_t)n * 64 + (m & 63)) * 32 + kw) * 64 + c];
            dst[m >> 6] = acc[nt][r];
        }
}

__global__ __launch_bounds__(256) void k3_spectral(const float2* __restrict__ X2,
                                                   const float* __restrict__ w0,
                                                   const float* __restrict__ w1,
                                                   unsigned* __restrict__ X3b) {
    __shared__ float2 WsP[4096];
    __shared__ float2 XsP[512];
    int t = threadIdx.x;
    int khIdx = blockIdx.x >> 5;
    int kw = blockIdx.x & 31;
    const float* wsrc = (khIdx < 32)
        ? (w0 + (size_t)(khIdx * 32 + kw) * (64 * 64 * 2))
        : (w1 + (size_t)((khIdx - 32) * 32 + kw) * (64 * 64 * 2));
    const float4* wsrc4 = (const float4*)wsrc;
#pragma unroll
    for (int k = 0; k < 8; ++k) {
        int idx = t + k * 256;
        float4 v = wsrc4[idx];
        WsP[2 * idx]     = make_float2(v.x * INVN, v.y * INVN);
        WsP[2 * idx + 1] = make_float2(v.z * INVN, v.w * INVN);
    }
#pragma unroll
    for (int k = 0; k < 2; ++k) {
        int id2 = t + k * 256;
        int n = id2 >> 6, c = id2 & 63;
        XsP[id2] = X2[(((size_t)n * KHN + khIdx) * KWN + kw) * CD + c];
    }
    __syncthreads();
    int o = t & 63;
    int ng = t >> 6;
#pragma unroll
    for (int p = 0; p < 2; ++p) {
        int n = ng + p * 4;
        float aR = 0.f, aI = 0.f;
#pragma unroll 8
        for (int i = 0; i < 64; ++i) {
            float2 xv = XsP[n * 64 + i];
            float2 wv_ = WsP[i * 64 + o];
            aR += xv.x * wv_.x - xv.y * wv_.y;
            aI += xv.x * wv_.y + xv.y * wv_.x;
        }
        X3b[(((size_t)n * 32 + kw) * 64 + khIdx) * 64 + o] = pack2(aR, aI);
    }
}

__global__ __launch_bounds__(256) void k4_idft_h(const unsigned* __restrict__ X3b,
                                                 const u16* __restrict__ A4g,
                                                 u16* __restrict__ Y1R,
                                                 u16* __restrict__ Y1I) {
    __shared__ __align__(16) u16 Bs[64 * 128];
    unsigned* B32 = (unsigned*)Bs;
    int t = threadIdx.x;
    int b = blockIdx.x;
    int n = b >> 7, kw = (b >> 2) & 31, mh = (b >> 1) & 1, ac = b & 1;
    const unsigned* src = X3b + ((size_t)n * 32 + kw) * (64 * 64);
#pragma unroll
    for (int it = 0; it < 8; ++it) {
        int idx = t + it * 256;
        int khl2 = idx >> 6;
        int o = idx & 63;
        unsigned vA = src[(2 * khl2) * 64 + o];
        unsigned vB = src[(2 * khl2 + 1) * 64 + o];
        int K = swkey(o) << 2;
        B32[o * 64 + (khl2 ^ K)]        = (vA & 0xFFFF) | (vB << 16);
        B32[o * 64 + ((32 + khl2) ^ K)] = (vA >> 16) | (vB & 0xFFFF0000u);
    }
    __syncthreads();
    int wv = t >> 6, l = t & 63, lm = l & 15, lq = l >> 4;
    u16* plane = mh ? Y1I : Y1R;
    f32x4 acc[2][4];
#pragma unroll
    for (int mt = 0; mt < 2; ++mt)
#pragma unroll
        for (int nt = 0; nt < 4; ++nt) { f32x4 z = {0.f, 0.f, 0.f, 0.f}; acc[mt][nt] = z; }
#pragma unroll
    for (int ks = 0; ks < 4; ++ks) {
        short8 a0 = *(const short8*)&A4g[(size_t)(mh * 256 + ac * 128 + wv * 32 + lm) * 128 + ks * 32 + lq * 8];
        short8 a1 = *(const short8*)&A4g[(size_t)(mh * 256 + ac * 128 + wv * 32 + 16 + lm) * 128 + ks * 32 + lq * 8];
#pragma unroll
        for (int nt = 0; nt < 4; ++nt) {
            int c = nt * 16 + lm;
            short8 bfr = *(const short8*)&Bs[c * 128 + ((ks * 32 + lq * 8) ^ (swkey(c) << 3))];
            acc[0][nt] = __builtin_amdgcn_mfma_f32_16x16x32_bf16(a0, bfr, acc[0][nt], 0, 0, 0);
            acc[1][nt] = __builtin_amdgcn_mfma_f32_16x16x32_bf16(a1, bfr, acc[1][nt], 0, 0, 0);
        }
    }
#pragma unroll
    for (int mt = 0; mt < 2; ++mt)
#pragma unroll
        for (int nt = 0; nt < 4; ++nt)
#pragma unroll
            for (int r = 0; r < 4; ++r) {
                int h = ac * 128 + wv * 32 + mt * 16 + lq * 4 + r;
                int o = nt * 16 + lm;
                plane[(((size_t)n * 256 + h) * 32 + kw) * 64 + o] = f2bf(acc[mt][nt][r]);
            }
}

__global__ __launch_bounds__(256) void k5_final(const u16* __restrict__ YRp,
                                                const u16* __restrict__ YIp,
                                                const float* __restrict__ x,
                                                const float* __restrict__ res_b,
                                                const u16* __restrict__ T5g,
                                                const u16* __restrict__ RWTg,
                                                float* __restrict__ out) {
    __shared__ __align__(16) u16 Xs[128 * 64];
    __shared__ __align__(16) u16 Bs[64 * 128];
    __shared__ float bs[64];
    unsigned* X32 = (unsigned*)Xs;
    unsigned* B32 = (unsigned*)Bs;
    int t = threadIdx.x;
    int nh = blockIdx.x >> 1, half = blockIdx.x & 1;
    if (t < 64) bs[t] = res_b[t];
    const float* xb = x + ((size_t)nh * 256 + half * 128) * 64;
#pragma unroll
    for (int it = 0; it < 8; ++it) {
        int idx = t + it * 256;
        int wl = idx >> 4, c4 = idx & 15;
        float4 f = *(const float4*)&xb[wl * 64 + c4 * 4];
        uint2 pv; pv.x = pack2(f.x, f.y); pv.y = pack2(f.z, f.w);
        *(uint2*)&X32[wl * 32 + ((2 * c4) ^ (swkey(wl) << 2))] = pv;
    }
    const u16* YR = YRp + (size_t)nh * 2048;
    const u16* YI = YIp + (size_t)nh * 2048;
#pragma unroll
    for (int it = 0; it < 4; ++it) {
        int part = it >> 1;
        int kw2 = t >> 4;
        int opb = (t & 15) + (it & 1) * 16;
        const u16* P = part ? YI : YR;
        unsigned vA = *(const unsigned*)&P[(2 * kw2) * 64 + 2 * opb];
        unsigned vB = *(const unsigned*)&P[(2 * kw2 + 1) * 64 + 2 * opb];
        int o0 = 2 * opb;
        int k2 = part * 16 + kw2;
        B32[o0 * 64 + (k2 ^ (swkey(o0) << 2))]       = (vA & 0xFFFF) | (vB << 16);
        B32[(o0 + 1) * 64 + (k2 ^ (swkey(o0 + 1) << 2))] = (vA >> 16) | (vB & 0xFFFF0000u);
    }
#pragma unroll
    for (int it = 0; it < 2; ++it) {
        int idx = t + it * 256;
        int o = idx >> 3, g = idx & 7;
        uint4 v = *(const uint4*)&RWTg[o * 64 + g * 8];
        *(uint4*)&B32[o * 64 + (8 + (g ^ swkey(o))) * 4] = v;
    }
    __syncthreads();
    int wv = t >> 6, l = t & 63, lm = l & 15, lq = l >> 4;
    f32x4 acc[2][4];
#pragma unroll
    for (int mt = 0; mt < 2; ++mt)
#pragma unroll
        for (int nt = 0; nt < 4; ++nt) { f32x4 z = {0.f, 0.f, 0.f, 0.f}; acc[mt][nt] = z; }
#pragma unroll
    for (int ks = 0; ks < 4; ++ks) {
        int r0 = wv * 32 + lm, r1 = r0 + 16;
        short8 a0, a1;
        if (ks < 2) {
            a0 = *(const short8*)&T5g[(half * 128 + r0) * 64 + ks * 32 + lq * 8];
            a1 = *(const short8*)&T5g[(half * 128 + r1) * 64 + ks * 32 + lq * 8];
        } else {
            a0 = *(const short8*)&Xs[r0 * 64 + (((ks - 2) * 32 + lq * 8) ^ (swkey(r0) << 3))];
            a1 = *(const short8*)&Xs[r1 * 64 + (((ks - 2) * 32 + lq * 8) ^ (swkey(r1) << 3))];
        }
#pragma unroll
        for (int nt = 0; nt < 4; ++nt) {
            int c = nt * 16 + lm;
            short8 bf = *(const short8*)&Bs[c * 128 + ((ks * 32 + lq * 8) ^ (swkey(c) << 3))];
            acc[0][nt] = __builtin_amdgcn_mfma_f32_16x16x32_bf16(a0, bf, acc[0][nt], 0, 0, 0);
            acc[1][nt] = __builtin_amdgcn_mfma_f32_16x16x32_bf16(a1, bf, acc[1][nt], 0, 0, 0);
        }
    }
    float* orow = out + ((size_t)nh * 256 + half * 128) * 64;
#pragma unroll
    for (int mt = 0; mt < 2; ++mt)
#pragma unroll
        for (int nt = 0; nt < 4; ++nt)
#pragma unroll
            for (int r = 0; r < 4; ++r) {
                int wloc = wv * 32 + mt * 16 + lq * 4 + r;
                int o = nt * 16 + lm;
                float v = acc[mt][nt][r] + bs[o];
                float sv = v / (1.0f + __expf(-v));
                orow[wloc * 64 + o] = sv;
            }
}

extern "C" void kernel_launch(void* const* d_in, const int* in_sizes, int n_in,
                              void* d_out, int out_size, void* d_ws, size_t ws_size,
                              hipStream_t stream) {
    const float* x     = (const float*)d_in[0];
    const float* w0    = (const float*)d_in[1];
    const float* w1    = (const float*)d_in[2];
    const float* res_w = (const float*)d_in[3];
    const float* res_b = (const float*)d_in[4];
    float* out = (float*)d_out;
    char* ws = (char*)d_ws;
    u16*      X1R  = (u16*)(ws);
    u16*      X1I  = (u16*)(ws + 8388608);
    float2*   X2   = (float2*)(ws + 16777216);
    unsigned* X3b  = (unsigned*)(ws + 25165824);
    u16*      Y1R  = (u16*)(ws + 33554432);
    u16*      Y1I  = (u16*)(ws + 41943040);
    u16*      A2g  = (u16*)(ws + 50331648);
    u16*      A4g  = (u16*)(ws + 50462720);
    u16*      T1g  = (u16*)(ws + 50593792);
    u16*      T5g  = (u16*)(ws + 50626560);
    u16*      RWTg = (u16*)(ws + 50659328);

    static int G = 0;
    if (G == 0) {
        int nb = 0;
        if (hipOccupancyMaxActiveBlocksPerMultiprocessor(&nb, mega, 256, 0) != hipSuccess || nb < 1)
            nb = 1;
        if (nb > 4) nb = 4;
        G = nb * 256;
    }

    void* args[] = { (void*)&x, (void*)&w0, (void*)&w1, (void*)&res_w, (void*)&res_b,
                     (void*)&X1R, (void*)&X1I, (void*)&X2, (void*)&X3b,
                     (void*)&Y1R, (void*)&Y1I, (void*)&A2g, (void*)&A4g,
                     (void*)&T1g, (void*)&T5g, (void*)&RWTg, (void*)&out };
    hipError_t e = hipLaunchCooperativeKernel((const void*)mega, dim3(G), dim3(256),
                                              args, 0, stream);
    if (e != hipSuccess) {
        // fallback: verified 6-kernel pipeline
        k0_tables  <<<256,          256, 0, stream>>>(A2g, A4g, T1g, T5g, res_w, RWTg);
        k1_dft_w   <<<NN * RR,      256, 0, stream>>>(x, T1g, X1R, X1I);
        k2_dft_h   <<<NN * KWN,     512, 0, stream>>>(X1R, X1I, A2g, X2);
        k3_spectral<<<KHN * KWN,    256, 0, stream>>>(X2, w0, w1, X3b);
        k4_idft_h  <<<NN * KWN * 4, 256, 0, stream>>>(X3b, A4g, Y1R, Y1I);
        k5_final   <<<NN * RR * 2,  256, 0, stream>>>(Y1R, Y1I, x, res_b, T5g, RWTg, out);
    }
}

// Round 3
// 378.517 us; speedup vs baseline: 2.3654x; 2.3654x over previous
//
#include <hip/hip_runtime.h>
#include <math.h>

#define NN 8
#define RR 256
#define CD 64      // in/out channel dim
#define MM 32      // kept modes per dim
#define KHN 64     // 2*MM kh values (rows 0..31 and 224..255)
#define KWN 32

#define ANG 0.024543692606170259f  // 2*pi/256
#define INVN (1.0f / 65536.0f)     // ortho norm

typedef __attribute__((ext_vector_type(4))) float f32x4;
typedef __attribute__((ext_vector_type(8))) short short8;
typedef unsigned short u16;

__device__ inline u16 f2bf(float f) {
    union { float f; unsigned u; } v; v.f = f;
    unsigned r = v.u + 0x7FFF + ((v.u >> 16) & 1);
    return (u16)(r >> 16);
}
__device__ inline unsigned pack2(float a, float b) {
    return (unsigned)f2bf(a) | ((unsigned)f2bf(b) << 16);
}
__device__ inline int swkey(int row) { return (row & 7) ^ ((row >> 3) & 7); }

// ---------------- K0: build twiddle operand tables (bf16) -------------------
__global__ __launch_bounds__(256) void k0_tables(u16* __restrict__ A2g,
                                                 u16* __restrict__ A4g,
                                                 u16* __restrict__ T1g,
                                                 u16* __restrict__ T5g,
                                                 const float* __restrict__ res_w,
                                                 u16* __restrict__ RWTg) {
    int gid = blockIdx.x * 256 + threadIdx.x;
    {
        int r = gid >> 9, k = gid & 511;
        int khIdx = r & 63, part = r >> 6;
        int kh = (khIdx < 32) ? khIdx : 192 + khIdx;
        int h = k & 255, kpart = k >> 8;
        float s, c;
        __sincosf((float)((kh * h) & 255) * ANG, &s, &c);
        float v = (part == 0) ? ((kpart == 0) ? c : s) : ((kpart == 0) ? -s : c);
        A2g[gid] = f2bf(v);
    }
    {
        int r = gid >> 7, k = gid & 127;
        int h = r & 255, part = r >> 8;
        int khIdx = k & 63, kpart = k >> 6;
        int kh = (khIdx < 32) ? khIdx : 192 + khIdx;
        float s, c;
        __sincosf((float)((kh * h) & 255) * ANG, &s, &c);
        float v = (part == 0) ? ((kpart == 0) ? c : -s) : ((kpart == 0) ? s : c);
        A4g[gid] = f2bf(v);
    }
    if (gid < 16384) {
        {
            int r = gid >> 8, w = gid & 255;
            float s, c;
            if (r < 32) { __sincosf((float)((r * w) & 255) * ANG, &s, &c); T1g[gid] = f2bf(c); }
            else        { __sincosf((float)(((r - 32) * w) & 255) * ANG, &s, &c); T1g[gid] = f2bf(-s); }
        }
        {
            int w = gid >> 6, c = gid & 63;
            float v;
            if (c == 0) v = 1.0f;
            else if (c < 32) { float s, co; __sincosf((float)((c * w) & 255) * ANG, &s, &co); v = 2.0f * co; }
            else if (c == 32) v = 0.0f;
            else { float s, co; __sincosf((float)(((c - 32) * w) & 255) * ANG, &s, &co); v = -2.0f * s; }
            T5g[gid] = f2bf(v);
        }
    }
    if (gid < 4096) {
        int o = gid >> 6, i = gid & 63;
        RWTg[gid] = f2bf(res_w[i * 64 + o]);
    }
}

// ---------------- K1: real DFT along w as bf16 MFMA GEMM (R1-verified) ------
__global__ __launch_bounds__(256) void k1_dft_w(const float* __restrict__ x,
                                                const u16* __restrict__ T1g,
                                                u16* __restrict__ X1R,
                                                u16* __restrict__ X1I) {
    __shared__ __align__(16) u16 Bt[64 * 256];
    unsigned* B32 = (unsigned*)Bt;
    int t = threadIdx.x;
    int nh = blockIdx.x;
    const float* xr = x + (size_t)nh * (RR * CD);
#pragma unroll
    for (int it = 0; it < 8; ++it) {
        int idx = t + it * 256;
        int q = idx >> 4;
        int c0 = (idx & 15) * 4;
        float4 f0 = *(const float4*)&xr[(2 * q) * 64 + c0];
        float4 f1 = *(const float4*)&xr[(2 * q + 1) * 64 + c0];
        B32[(c0 + 0) * 128 + (q ^ (swkey(c0 + 0) << 2))] = pack2(f0.x, f1.x);
        B32[(c0 + 1) * 128 + (q ^ (swkey(c0 + 1) << 2))] = pack2(f0.y, f1.y);
        B32[(c0 + 2) * 128 + (q ^ (swkey(c0 + 2) << 2))] = pack2(f0.z, f1.z);
        B32[(c0 + 3) * 128 + (q ^ (swkey(c0 + 3) << 2))] = pack2(f0.w, f1.w);
    }
    __syncthreads();
    int wv = t >> 6, l = t & 63, lm = l & 15, lq = l >> 4;
    f32x4 acc[4];
#pragma unroll
    for (int nt = 0; nt < 4; ++nt) { f32x4 z = {0.f, 0.f, 0.f, 0.f}; acc[nt] = z; }
#pragma unroll
    for (int ks = 0; ks < 8; ++ks) {
        short8 a = *(const short8*)&T1g[(wv * 16 + lm) * 256 + ks * 32 + lq * 8];
#pragma unroll
        for (int nt = 0; nt < 4; ++nt) {
            int c = nt * 16 + lm;
            short8 bf = *(const short8*)&Bt[c * 256 + ((ks * 32 + lq * 8) ^ (swkey(c) << 3))];
            acc[nt] = __builtin_amdgcn_mfma_f32_16x16x32_bf16(a, bf, acc[nt], 0, 0, 0);
        }
    }
    int n = nh >> 8, h = nh & 255;
#pragma unroll
    for (int nt = 0; nt < 4; ++nt)
#pragma unroll
        for (int r = 0; r < 4; ++r) {
            int kwp = wv * 16 + lq * 4 + r;
            int cc = nt * 16 + lm;
            u16 v = f2bf(acc[nt][r]);
            if (kwp < 32) X1R[(((size_t)n * 32 + kwp) * 256 + h) * 64 + cc] = v;
            else          X1I[(((size_t)n * 32 + (kwp - 32)) * 256 + h) * 64 + cc] = v;
        }
}

// ------- K234: fused DFT-h + spectral matmul + iDFT-h, one (n,kw) per block -
// Phase A = R1 k2 (DFT-h, MFMA, X2 kept in LDS)
// Phase B = R1 k3 re-indexed per-kh (complex 64x64, weights from global/L2)
// Phase C = R1 k4 (iDFT-h, MFMA, B operand from LDS)
__global__ __launch_bounds__(512) void k234(const u16* __restrict__ X1R,
                                            const u16* __restrict__ X1I,
                                            const u16* __restrict__ A2g,
                                            const float* __restrict__ w0,
                                            const float* __restrict__ w1,
                                            const u16* __restrict__ A4g,
                                            u16* __restrict__ Y1R,
                                            u16* __restrict__ Y1I) {
    __shared__ __align__(16) unsigned char SMEM[49664];
    u16* Bs0 = (u16*)SMEM;                    // 16 KB  (phase A chunk buf)
    u16* Bs1 = (u16*)(SMEM + 16384);          // 16 KB  (phase A chunk buf)
    float* Xsp = (float*)SMEM;                // [2][64][65] f32 = 33280 B (over Bs)
    u16* X3s = (u16*)(SMEM + 33280);          // [64][128] u16 = 16 KB
    int t = threadIdx.x;
    int n = blockIdx.x >> 5, kw = blockIdx.x & 31;
    const u16* baseR = X1R + ((size_t)n * 32 + kw) * (256 * 64);
    const u16* baseI = X1I + ((size_t)n * 32 + kw) * (256 * 64);
    int wv = t >> 6, l = t & 63, lm = l & 15, lq = l >> 4;

    // ---- phase A: X2[128 x 64] = A2[128x512] @ B[512x64] ----
    f32x4 acc[4];
#pragma unroll
    for (int nt = 0; nt < 4; ++nt) { f32x4 z = {0.f, 0.f, 0.f, 0.f}; acc[nt] = z; }
    auto stage = [&](int ck, u16* B) {
        const u16* src = ((ck < 2) ? baseR : baseI) + (size_t)(ck & 1) * (128 * 64);
#pragma unroll
        for (int it = 0; it < 2; ++it) {
            int idx = t + it * 512;
            int hh = idx >> 3, g = idx & 7;
            short8 v = *(const short8*)&src[hh * 64 + g * 8];
#pragma unroll
            for (int j = 0; j < 8; ++j) {
                int c = g * 8 + j;
                B[c * 128 + (hh ^ (swkey(c) << 3))] = (u16)v[j];
            }
        }
    };
    stage(0, Bs0);
    __syncthreads();
    for (int ck = 0; ck < 4; ++ck) {
        if (ck < 3) stage(ck + 1, ((ck + 1) & 1) ? Bs1 : Bs0);
        const u16* B = (ck & 1) ? Bs1 : Bs0;
#pragma unroll
        for (int ks = 0; ks < 4; ++ks) {
            short8 a = *(const short8*)&A2g[(wv * 16 + lm) * 512 + ck * 128 + ks * 32 + lq * 8];
#pragma unroll
            for (int nt = 0; nt < 4; ++nt) {
                int c = nt * 16 + lm;
                short8 bf = *(const short8*)&B[c * 128 + ((ks * 32 + lq * 8) ^ (swkey(c) << 3))];
                acc[nt] = __builtin_amdgcn_mfma_f32_16x16x32_bf16(a, bf, acc[nt], 0, 0, 0);
            }
        }
        __syncthreads();
    }
    // write X2 into LDS (Bs area is dead now)
#pragma unroll
    for (int nt = 0; nt < 4; ++nt)
#pragma unroll
        for (int r = 0; r < 4; ++r) {
            int m = wv * 16 + lq * 4 + r;          // 0..127
            int c = nt * 16 + lm;
            Xsp[(m >> 6) * 4160 + (m & 63) * 65 + c] = acc[nt][r];
        }
    __syncthreads();

    // ---- phase B: per-kh complex 64x64 channel matmul ----
    {
        int o = t & 63, g = t >> 6;                // 8 groups x 8 kh each
#pragma unroll
        for (int jj = 0; jj < 8; ++jj) {
            int kh = g * 8 + jj;
            const float2* wb = (const float2*)((kh < 32)
                ? (w0 + (size_t)(kh * 32 + kw) * (64 * 64 * 2))
                : (w1 + (size_t)((kh - 32) * 32 + kw) * (64 * 64 * 2)));
            float aR = 0.f, aI = 0.f;
#pragma unroll 8
            for (int i = 0; i < 64; ++i) {
                float xr = Xsp[kh * 65 + i];
                float xi = Xsp[4160 + kh * 65 + i];
                float2 w2 = wb[i * 64 + o];
                aR += xr * w2.x - xi * w2.y;
                aI += xr * w2.y + xi * w2.x;
            }
            int s3 = swkey(o) << 3;
            X3s[o * 128 + (kh ^ s3)]        = f2bf(aR * INVN);
            X3s[o * 128 + ((64 + kh) ^ s3)] = f2bf(aI * INVN);
        }
    }
    __syncthreads();

    // ---- phase C: Y[2][256 x 64] = A4[512x128] @ X3s[128x64] ----
#pragma unroll
    for (int mh = 0; mh < 2; ++mh) {
        u16* plane = mh ? Y1I : Y1R;
#pragma unroll
        for (int ac = 0; ac < 2; ++ac) {
            f32x4 acc2[4];
#pragma unroll
            for (int nt = 0; nt < 4; ++nt) { f32x4 z = {0.f, 0.f, 0.f, 0.f}; acc2[nt] = z; }
#pragma unroll
            for (int ks = 0; ks < 4; ++ks) {
                short8 a = *(const short8*)&A4g[(size_t)(mh * 256 + ac * 128 + wv * 16 + lm) * 128 + ks * 32 + lq * 8];
#pragma unroll
                for (int nt = 0; nt < 4; ++nt) {
                    int c = nt * 16 + lm;
                    short8 bfr = *(const short8*)&X3s[c * 128 + ((ks * 32 + lq * 8) ^ (swkey(c) << 3))];
                    acc2[nt] = __builtin_amdgcn_mfma_f32_16x16x32_bf16(a, bfr, acc2[nt], 0, 0, 0);
                }
            }
#pragma unroll
            for (int nt = 0; nt < 4; ++nt)
#pragma unroll
                for (int r = 0; r < 4; ++r) {
                    int h = ac * 128 + wv * 16 + lq * 4 + r;
                    int o = nt * 16 + lm;
                    plane[(((size_t)n * 256 + h) * 32 + kw) * 64 + o] = f2bf(acc2[nt][r]);
                }
        }
    }
}

// ------- K5: fused c2r-synthesis + residual GEMM + bias + SiLU (R1-verified)
__global__ __launch_bounds__(256) void k5_final(const u16* __restrict__ YRp,
                                                const u16* __restrict__ YIp,
                                                const float* __restrict__ x,
                                                const float* __restrict__ res_b,
                                                const u16* __restrict__ T5g,
                                                const u16* __restrict__ RWTg,
                                                float* __restrict__ out) {
    __shared__ __align__(16) u16 Xs[128 * 64];
    __shared__ __align__(16) u16 Bs[64 * 128];
    __shared__ float bs[64];
    unsigned* X32 = (unsigned*)Xs;
    unsigned* B32 = (unsigned*)Bs;
    int t = threadIdx.x;
    int nh = blockIdx.x >> 1, half = blockIdx.x & 1;
    if (t < 64) bs[t] = res_b[t];
    const float* xb = x + ((size_t)nh * 256 + half * 128) * 64;
#pragma unroll
    for (int it = 0; it < 8; ++it) {
        int idx = t + it * 256;
        int wl = idx >> 4, c4 = idx & 15;
        float4 f = *(const float4*)&xb[wl * 64 + c4 * 4];
        uint2 pv; pv.x = pack2(f.x, f.y); pv.y = pack2(f.z, f.w);
        *(uint2*)&X32[wl * 32 + ((2 * c4) ^ (swkey(wl) << 2))] = pv;
    }
    const u16* YR = YRp + (size_t)nh * 2048;
    const u16* YI = YIp + (size_t)nh * 2048;
#pragma unroll
    for (int it = 0; it < 4; ++it) {
        int part = it >> 1;
        int kw2 = t >> 4;
        int opb = (t & 15) + (it & 1) * 16;
        const u16* P = part ? YI : YR;
        unsigned vA = *(const unsigned*)&P[(2 * kw2) * 64 + 2 * opb];
        unsigned vB = *(const unsigned*)&P[(2 * kw2 + 1) * 64 + 2 * opb];
        int o0 = 2 * opb;
        int k2 = part * 16 + kw2;
        B32[o0 * 64 + (k2 ^ (swkey(o0) << 2))]           = (vA & 0xFFFF) | (vB << 16);
        B32[(o0 + 1) * 64 + (k2 ^ (swkey(o0 + 1) << 2))] = (vA >> 16) | (vB & 0xFFFF0000u);
    }
#pragma unroll
    for (int it = 0; it < 2; ++it) {
        int idx = t + it * 256;
        int o = idx >> 3, g = idx & 7;
        uint4 v = *(const uint4*)&RWTg[o * 64 + g * 8];
        *(uint4*)&B32[o * 64 + (8 + (g ^ swkey(o))) * 4] = v;
    }
    __syncthreads();
    int wv = t >> 6, l = t & 63, lm = l & 15, lq = l >> 4;
    f32x4 acc[2][4];
#pragma unroll
    for (int mt = 0; mt < 2; ++mt)
#pragma unroll
        for (int nt = 0; nt < 4; ++nt) { f32x4 z = {0.f, 0.f, 0.f, 0.f}; acc[mt][nt] = z; }
#pragma unroll
    for (int ks = 0; ks < 4; ++ks) {
        int r0 = wv * 32 + lm, r1 = r0 + 16;
        short8 a0, a1;
        if (ks < 2) {
            a0 = *(const short8*)&T5g[(half * 128 + r0) * 64 + ks * 32 + lq * 8];
            a1 = *(const short8*)&T5g[(half * 128 + r1) * 64 + ks * 32 + lq * 8];
        } else {
            a0 = *(const short8*)&Xs[r0 * 64 + (((ks - 2) * 32 + lq * 8) ^ (swkey(r0) << 3))];
            a1 = *(const short8*)&Xs[r1 * 64 + (((ks - 2) * 32 + lq * 8) ^ (swkey(r1) << 3))];
        }
#pragma unroll
        for (int nt = 0; nt < 4; ++nt) {
            int c = nt * 16 + lm;
            short8 bf = *(const short8*)&Bs[c * 128 + ((ks * 32 + lq * 8) ^ (swkey(c) << 3))];
            acc[0][nt] = __builtin_amdgcn_mfma_f32_16x16x32_bf16(a0, bf, acc[0][nt], 0, 0, 0);
            acc[1][nt] = __builtin_amdgcn_mfma_f32_16x16x32_bf16(a1, bf, acc[1][nt], 0, 0, 0);
        }
    }
    float* orow = out + ((size_t)nh * 256 + half * 128) * 64;
#pragma unroll
    for (int mt = 0; mt < 2; ++mt)
#pragma unroll
        for (int nt = 0; nt < 4; ++nt)
#pragma unroll
            for (int r = 0; r < 4; ++r) {
                int wloc = wv * 32 + mt * 16 + lq * 4 + r;
                int o = nt * 16 + lm;
                float v = acc[mt][nt][r] + bs[o];
                float sv = v / (1.0f + __expf(-v));
                orow[wloc * 64 + o] = sv;
            }
}

extern "C" void kernel_launch(void* const* d_in, const int* in_sizes, int n_in,
                              void* d_out, int out_size, void* d_ws, size_t ws_size,
                              hipStream_t stream) {
    const float* x     = (const float*)d_in[0];
    const float* w0    = (const float*)d_in[1];
    const float* w1    = (const float*)d_in[2];
    const float* res_w = (const float*)d_in[3];
    const float* res_b = (const float*)d_in[4];
    float* out = (float*)d_out;
    char* ws = (char*)d_ws;
    u16* X1R  = (u16*)(ws);
    u16* X1I  = (u16*)(ws + 8388608);
    u16* Y1R  = (u16*)(ws + 33554432);
    u16* Y1I  = (u16*)(ws + 41943040);
    u16* A2g  = (u16*)(ws + 50331648);
    u16* A4g  = (u16*)(ws + 50462720);
    u16* T1g  = (u16*)(ws + 50593792);
    u16* T5g  = (u16*)(ws + 50626560);
    u16* RWTg = (u16*)(ws + 50659328);

    k0_tables<<<256,         256, 0, stream>>>(A2g, A4g, T1g, T5g, res_w, RWTg);
    k1_dft_w <<<NN * RR,     256, 0, stream>>>(x, T1g, X1R, X1I);
    k234     <<<NN * KWN,    512, 0, stream>>>(X1R, X1I, A2g, w0, w1, A4g, Y1R, Y1I);
    k5_final <<<NN * RR * 2, 256, 0, stream>>>(Y1R, Y1I, x, res_b, T5g, RWTg, out);
}